// Round 21
// baseline (28.117 us; speedup 1.0000x reference)
//
#include <hip/hip_runtime.h>

// ForegroundConsistencyLoss — N=8192, C=20.
// loss = mean over pairs {both fg, d2>4} of relu(cos_sim(logits_i, logits_j)).
//
// v6 (FINAL, measured best 18.86us): fused prep+pairs + tiny final reduce.
// Each block owns a 128x256 super-tile (4 rowgroups x 8 colgroups), preps
// its own 384 points into LDS fragments, runs 32 MFMA tiles (8/wave),
// triangle-weighted (skip cg<rg, x2 cg>rg, x1 diag). Per-block partials,
// zero contended atomics.
//
// Evidence ledger (why this shape): v3 contended atomics=+44us; v7
// grid.sync=+60us; v9 4B-memset node=+22us -> all 1-dispatch reduction
// tricks cost more than the second dispatch they replace. v10 (1056-block
// 1D triangle) = 20.3us vs this 18.9us -> within noise, keep measured best.
// Per-dispatch graph overhead ~6-7us dominates; kernel work ~5-6us.

#define C_CLS 20

typedef __attribute__((ext_vector_type(8)))  short bh8;    // 8 bf16 (4 VGPRs)
typedef __attribute__((ext_vector_type(16))) float fx16;   // 16 f32 acc
typedef __attribute__((ext_vector_type(4)))  float f4;

static __device__ __forceinline__ short f2bf(float x) {
    unsigned u = __float_as_uint(x);
    unsigned r = (u + 0x7fffu + ((u >> 16) & 1u)) >> 16;
    return (short)r;
}

struct Rec { bh8 v0, v1, v2, d; };

// Build one point's fragments. bside=false -> d is the A'-row
// [-2x,-2y,-2z,sq',1]; bside=true -> d is the B'-col [x,y,z,1,sq'].
static __device__ __forceinline__ Rec make_rec(const float* __restrict__ pc,
                                               const float* __restrict__ logits,
                                               int i, bool bside) {
    const f4* lg4 = (const f4*)(logits + (size_t)i * C_CLS);  // 80B stride, 16B ok
    float l[C_CLS];
#pragma unroll
    for (int q = 0; q < 5; ++q) {
        f4 v = lg4[q];
        l[q * 4 + 0] = v.x; l[q * 4 + 1] = v.y; l[q * 4 + 2] = v.z; l[q * 4 + 3] = v.w;
    }
    float m = l[1];
#pragma unroll
    for (int k = 2; k < C_CLS; ++k) m = fmaxf(m, l[k]);
    bool fg = m > l[0];                 // argmax != 0 (ties -> idx 0 -> bg)
    float ss = 0.f;
#pragma unroll
    for (int k = 0; k < C_CLS; ++k) ss = fmaf(l[k], l[k], ss);
    float inv = 1.0f / fmaxf(sqrtf(ss), 1e-8f);
    float px = pc[i * 3 + 0], py = pc[i * 3 + 1], pz = pc[i * 3 + 2];
    float sq = px * px + py * py + pz * pz;
    float sqp = fg ? sq : -1.0e30f;

    Rec rec;
    bh8 vz = {0, 0, 0, 0, 0, 0, 0, 0};
#pragma unroll
    for (int e = 0; e < 8; ++e) rec.v0[e] = f2bf(l[e] * inv);
#pragma unroll
    for (int e = 0; e < 8; ++e) rec.v1[e] = f2bf(l[8 + e] * inv);
    rec.v2 = vz;
#pragma unroll
    for (int e = 0; e < 4; ++e) rec.v2[e] = f2bf(l[16 + e] * inv);
    bh8 d = vz;
    if (!bside) {
        d[0] = f2bf(-2.0f * px); d[1] = f2bf(-2.0f * py); d[2] = f2bf(-2.0f * pz);
        d[3] = f2bf(sqp);        d[4] = f2bf(1.0f);
    } else {
        d[0] = f2bf(px); d[1] = f2bf(py); d[2] = f2bf(pz);
        d[3] = f2bf(1.0f); d[4] = f2bf(sqp);
    }
    rec.d = d;
    return rec;
}

// super-tile: 4 row-groups x 8 col-groups of 32 points each.
// grid = dim3(NG/8, NG/4) = (32, 64); block included iff 8C+7 >= 4R.
__global__ void __launch_bounds__(256) fcl_fused(const float* __restrict__ pc,
                                                 const float* __restrict__ logits,
                                                 float* __restrict__ psums,
                                                 int* __restrict__ pcnts) {
    const int tid = threadIdx.x;
    const int C = blockIdx.x, R = blockIdx.y;
    const int bid = R * gridDim.x + C;

    if (8 * C + 7 < 4 * R) {             // entirely below diagonal
        if (tid == 0) { psums[bid] = 0.f; pcnts[bid] = 0; }
        return;
    }

    __shared__ bh8 shAS[4 * 2 * 64];     // 8 KB: A-side sim frags
    __shared__ bh8 shAD[4 * 64];         // 4 KB: A-side dist frags
    __shared__ bh8 shBS[8 * 2 * 64];     // 16 KB: B-side sim frags
    __shared__ bh8 shBD[8 * 64];         // 8 KB: B-side dist frags

    const bh8 vz = {0, 0, 0, 0, 0, 0, 0, 0};

    // prep B region: 256 points at C*256
    {
        int idx = tid;                    // 0..255
        Rec rec = make_rec(pc, logits, C * 256 + idx, true);
        int g = idx >> 5, r = idx & 31;
        shBS[(g * 2 + 0) * 64 + r]      = rec.v0;
        shBS[(g * 2 + 0) * 64 + r + 32] = rec.v1;
        shBS[(g * 2 + 1) * 64 + r]      = rec.v2;
        shBS[(g * 2 + 1) * 64 + r + 32] = vz;
        shBD[g * 64 + r]                = rec.d;
        shBD[g * 64 + r + 32]           = vz;
    }
    // prep A region: 128 points at R*128 (threads 0..127)
    if (tid < 128) {
        int idx = tid;
        Rec rec = make_rec(pc, logits, R * 128 + idx, false);
        int g = idx >> 5, r = idx & 31;
        shAS[(g * 2 + 0) * 64 + r]      = rec.v0;
        shAS[(g * 2 + 0) * 64 + r + 32] = rec.v1;
        shAS[(g * 2 + 1) * 64 + r]      = rec.v2;
        shAS[(g * 2 + 1) * 64 + r + 32] = vz;
        shAD[g * 64 + r]                = rec.d;
        shAD[g * 64 + r + 32]           = vz;
    }
    __syncthreads();

    const int lane = tid & 63;
    const int w = tid >> 6;               // wave = local row-group 0..3
    const int rg = R * 4 + w;             // global row-group

    const bh8 aS0 = shAS[(w * 2 + 0) * 64 + lane];
    const bh8 aS1 = shAS[(w * 2 + 1) * 64 + lane];
    const bh8 aD  = shAD[w * 64 + lane];

    float psD = 0.f, psO = 0.f;
    int   cnD = 0,   cnO = 0;

#pragma unroll
    for (int k = 0; k < 8; ++k) {
        const int cg = C * 8 + k;         // global col-group (wave-uniform)
        if (cg < rg) continue;            // below diagonal: skip
        bh8 b0 = shBS[(k * 2 + 0) * 64 + lane];
        bh8 b1 = shBS[(k * 2 + 1) * 64 + lane];
        bh8 bd = shBD[k * 64 + lane];
        fx16 accS = {0.f};
        accS = __builtin_amdgcn_mfma_f32_32x32x16_bf16(aS0, b0, accS, 0, 0, 0);
        accS = __builtin_amdgcn_mfma_f32_32x32x16_bf16(aS1, b1, accS, 0, 0, 0);
        fx16 accD = {0.f};
        accD = __builtin_amdgcn_mfma_f32_32x32x16_bf16(aD, bd, accD, 0, 0, 0);
        if (cg == rg) {
#pragma unroll
            for (int r2 = 0; r2 < 16; ++r2) {
                bool cc = accD[r2] > 4.0f;
                psD += cc ? fmaxf(accS[r2], 0.f) : 0.f;
                cnD += cc ? 1 : 0;
            }
        } else {
#pragma unroll
            for (int r2 = 0; r2 < 16; ++r2) {
                bool cc = accD[r2] > 4.0f;
                psO += cc ? fmaxf(accS[r2], 0.f) : 0.f;
                cnO += cc ? 1 : 0;
            }
        }
    }

    // fold x2 off-diagonal weight, wave + block reduce
    float ps = psD + 2.0f * psO;
    int   cn = cnD + 2 * cnO;
#pragma unroll
    for (int off = 32; off > 0; off >>= 1) {
        ps += __shfl_down(ps, off);
        cn += __shfl_down(cn, off);
    }
    __shared__ float sps[4];
    __shared__ int   scs[4];
    if (lane == 0) { sps[w] = ps; scs[w] = cn; }
    __syncthreads();
    if (tid == 0) {
        psums[bid] = sps[0] + sps[1] + sps[2] + sps[3];
        pcnts[bid] = scs[0] + scs[1] + scs[2] + scs[3];
    }
}

__global__ void __launch_bounds__(256) fcl_final(const float* __restrict__ psums,
                                                 const int* __restrict__ pcnts,
                                                 float* __restrict__ out, int nb) {
    float s = 0.f;
    int c = 0;
    for (int k = threadIdx.x; k < nb; k += 256) { s += psums[k]; c += pcnts[k]; }
#pragma unroll
    for (int off = 32; off > 0; off >>= 1) {
        s += __shfl_down(s, off);
        c += __shfl_down(c, off);
    }
    __shared__ float sps[4];
    __shared__ int   scs[4];
    int wid = threadIdx.x >> 6, lane = threadIdx.x & 63;
    if (lane == 0) { sps[wid] = s; scs[wid] = c; }
    __syncthreads();
    if (threadIdx.x == 0) {
        float ts = sps[0] + sps[1] + sps[2] + sps[3];
        int   tc = scs[0] + scs[1] + scs[2] + scs[3];
        out[0] = (tc > 0) ? ts / (float)tc : 1.0f;
    }
}

extern "C" void kernel_launch(void* const* d_in, const int* in_sizes, int n_in,
                              void* d_out, int out_size, void* d_ws, size_t ws_size,
                              hipStream_t stream) {
    const float* pc     = (const float*)d_in[0];  // [N,3]
    const float* logits = (const float*)d_in[1];  // [N,20]
    float* out = (float*)d_out;

    const int N = in_sizes[0] / 3;                // 8192
    const int NG = N / 32;                        // 256 groups
    const int gx = NG / 8;                        // 32 super-cols
    const int gy = NG / 4;                        // 64 super-rows
    const int nb = gx * gy;                       // 2048 partial slots

    float* psums = (float*)d_ws;
    int*   pcnts = (int*)(psums + nb);

    fcl_fused<<<dim3(gx, gy), 256, 0, stream>>>(pc, logits, psums, pcnts);
    fcl_final<<<1, 256, 0, stream>>>(psums, pcnts, out, nb);
}